// Round 6
// baseline (742.300 us; speedup 1.0000x reference)
//
#include <hip/hip_runtime.h>
#include <hip/hip_bf16.h>
#include <stdint.h>

#define L 1024
#define D 1024
#define NLAYER 4
#define NSTATE 16
#define DI 2048
#define DTR 64
#define KCONV 4
#define XD 96      // DTR + 2*NSTATE
#define NC 64      // scan chunks
#define CT 16      // timesteps per chunk (L/NC)
#define KSPLIT 16  // x_proj split-K (atomic epilogue)
#define OSPLIT 4   // out_proj split-K (part2 + reduce)
#define BK 32
#define DIST 4     // GEMM prefetch depth (iterations)

typedef __attribute__((ext_vector_type(8))) short short8;
typedef __attribute__((ext_vector_type(4))) float floatx4;

__device__ __forceinline__ float siluf(float x) { return x / (1.f + __expf(-x)); }

__device__ __forceinline__ unsigned short f2bf(float x) {
    __hip_bfloat16 b = __float2bfloat16(x);
    return *reinterpret_cast<unsigned short*>(&b);
}

__device__ __forceinline__ short8 pack8(floatx4 a, floatx4 b) {
    short8 o;
    o[0] = (short)f2bf(a.x); o[1] = (short)f2bf(a.y);
    o[2] = (short)f2bf(a.z); o[3] = (short)f2bf(a.w);
    o[4] = (short)f2bf(b.x); o[5] = (short)f2bf(b.y);
    o[6] = (short)f2bf(b.z); o[7] = (short)f2bf(b.w);
    return o;
}

// ---------- device-scope (sc1) accessors for cross-block traffic within one dispatch ----------
__device__ __forceinline__ void st_dev_u32(uint32_t* p, uint32_t v) {
    __hip_atomic_store(p, v, __ATOMIC_RELAXED, __HIP_MEMORY_SCOPE_AGENT);
}
__device__ __forceinline__ uint32_t ld_dev_u32(const uint32_t* p) {
    return __hip_atomic_load(p, __ATOMIC_RELAXED, __HIP_MEMORY_SCOPE_AGENT);
}
__device__ __forceinline__ void st_dev_u64(void* p, uint64_t v) {
    __hip_atomic_store((unsigned long long*)p, (unsigned long long)v, __ATOMIC_RELAXED, __HIP_MEMORY_SCOPE_AGENT);
}
__device__ __forceinline__ uint64_t ld_dev_u64(const void* p) {
    return (uint64_t)__hip_atomic_load((const unsigned long long*)p, __ATOMIC_RELAXED, __HIP_MEMORY_SCOPE_AGENT);
}
__device__ __forceinline__ float ld_dev_f(const float* p) {
    uint32_t u = ld_dev_u32((const uint32_t*)p);
    union { uint32_t u; float f; } c; c.u = u;
    return c.f;
}
__device__ __forceinline__ void st_dev_f(float* p, float v) {
    union { float f; uint32_t u; } c; c.f = v;
    st_dev_u32((uint32_t*)p, c.u);
}

// Barrier that does NOT drain vmcnt: deep global-load prefetches stay in flight.
#define BARRIER_NODRAIN() asm volatile("s_waitcnt lgkmcnt(0)\n\ts_barrier" ::: "memory")

// ---------------- RMSNorm (layer 0) -> bf16; block 0 also zeroes the scan flags ----------------
__global__ __launch_bounds__(256) void rmsnorm_kernel(const float* __restrict__ x,
                                                      const float* __restrict__ w,
                                                      __hip_bfloat16* __restrict__ xn,
                                                      uint32_t* __restrict__ flags) {
    if (blockIdx.x == 0) {
#pragma unroll
        for (int i = 0; i < 3; ++i) st_dev_u32(&flags[threadIdx.x + i * 256], 0u);
    }
    int row = blockIdx.x;
    const float* xr = x + (size_t)row * D;
    float v[4];
    float s = 0.f;
#pragma unroll
    for (int i = 0; i < 4; ++i) {
        v[i] = xr[threadIdx.x + i * 256];
        s += v[i] * v[i];
    }
#pragma unroll
    for (int off = 32; off > 0; off >>= 1) s += __shfl_xor(s, off, 64);
    __shared__ float red[4];
    int wave = threadIdx.x >> 6;
    if ((threadIdx.x & 63) == 0) red[wave] = s;
    __syncthreads();
    float inv = rsqrtf((red[0] + red[1] + red[2] + red[3]) * (1.f / D) + 1e-5f);
#pragma unroll
    for (int i = 0; i < 4; ++i) {
        int c = threadIdx.x + i * 256;
        xn[(size_t)row * D + c] = __float2bfloat16(v[i] * inv * w[c]);
    }
}

// ---------------- pipelined GEMM (128x64 tile): C[M,N] = A[M,K] * B[N,K]^T ----------------
// A bf16 (AF32=false) or f32 converted during staging (AF32=true); B fp32 -> bf16.
// EPI: 0 plain store; 1 softplus(c + bias[n]) store; 2 atomicAdd (split-K accumulate).
template <int EPI, int ITERS, bool AF32, int QD>
__global__ __launch_bounds__(256, 2) void gemm_pipe(
    const void* __restrict__ Aptr, int lda,
    const float* __restrict__ Bw, int ldb, int Brows,
    float* __restrict__ C, int ldc, int Nvalid,
    const float* __restrict__ bias) {
    __shared__ __align__(16) __hip_bfloat16 As[2][128 * BK];
    __shared__ __align__(16) __hip_bfloat16 Bs[2][64 * BK];
    int tid = threadIdx.x;
    int wave = tid >> 6, lane = tid & 63;

    int gxy = gridDim.x * gridDim.y;
    int total = gxy * gridDim.z;
    int flat = (blockIdx.z * gridDim.y + blockIdx.y) * gridDim.x + blockIdx.x;
    int bm, bn, bz;
    if ((total & 7) == 0) {
        int lid = (flat & 7) * (total >> 3) + (flat >> 3);
        bz = lid / gxy;
        int rem = lid - bz * gxy;
        bn = rem / gridDim.y;
        bm = rem - bn * gridDim.y;
    } else {
        bm = blockIdx.y; bn = blockIdx.x; bz = blockIdx.z;
    }

    int m0 = bm * 128, n0 = bn * 64;
    int k_base = bz * (ITERS * BK);
    int wr = wave >> 1, wc = wave & 1;
    int srow = lane >> 2, scol = (lane & 3) * 8;
    int q = lane >> 4, r = lane & 15;

    floatx4 acc[4][2] = {};

    int arow0 = m0 + wave * 32 + srow;
    const __hip_bfloat16* gA0 = nullptr; const __hip_bfloat16* gA1 = nullptr;
    const float* gAf0 = nullptr; const float* gAf1 = nullptr;
    if (AF32) {
        gAf0 = (const float*)Aptr + (long)arow0 * lda + scol + k_base;
        gAf1 = gAf0 + (long)16 * lda;
    } else {
        gA0 = (const __hip_bfloat16*)Aptr + (long)arow0 * lda + scol + k_base;
        gA1 = gA0 + (long)16 * lda;
    }
    int bnrow = n0 + wave * 16 + srow;
    const float* gB = Bw + (long)bnrow * ldb + scol + k_base;
    bool bok = bnrow < Brows;

    short8 qa0[QD], qa1[QD];
    floatx4 qaf[AF32 ? QD : 1][4];
    floatx4 qb0[QD] = {}, qb1[QD] = {};

    auto ld = [&](int j) {
        int k0 = j * BK;
        int s = j & (QD - 1);
        if (AF32) {
            qaf[s][0] = *(const floatx4*)(gAf0 + k0);
            qaf[s][1] = *(const floatx4*)(gAf0 + k0 + 4);
            qaf[s][2] = *(const floatx4*)(gAf1 + k0);
            qaf[s][3] = *(const floatx4*)(gAf1 + k0 + 4);
        } else {
            qa0[s] = *(const short8*)(gA0 + k0);
            qa1[s] = *(const short8*)(gA1 + k0);
        }
        if (bok) {
            qb0[s] = *(const floatx4*)(gB + k0);
            qb1[s] = *(const floatx4*)(gB + k0 + 4);
        }
    };
    auto wrstage = [&](int j) {
        int p = j & 1, s = j & (QD - 1);
        if (AF32) {
            *(short8*)(&As[p][(wave * 32 + srow) * BK + scol]) = pack8(qaf[s][0], qaf[s][1]);
            *(short8*)(&As[p][(wave * 32 + 16 + srow) * BK + scol]) = pack8(qaf[s][2], qaf[s][3]);
        } else {
            *(short8*)(&As[p][(wave * 32 + srow) * BK + scol]) = qa0[s];
            *(short8*)(&As[p][(wave * 32 + 16 + srow) * BK + scol]) = qa1[s];
        }
        *(short8*)(&Bs[p][(wave * 16 + srow) * BK + scol]) = pack8(qb0[s], qb1[s]);
    };

#pragma unroll
    for (int j = 0; j < QD; ++j)
        if (j < ITERS) ld(j);
    wrstage(0);

#pragma unroll
    for (int k = 0; k < ITERS; ++k) {
        BARRIER_NODRAIN();
        if (k + QD < ITERS) ld(k + QD);
        if (k + 1 < ITERS) wrstage(k + 1);
        const short* Ap = (const short*)As[k & 1];
        const short* Bp = (const short*)Bs[k & 1];
        short8 af[4], bfr[2];
#pragma unroll
        for (int i = 0; i < 4; ++i)
            af[i] = *(const short8*)(Ap + (wr * 64 + i * 16 + r) * BK + q * 8);
#pragma unroll
        for (int j = 0; j < 2; ++j)
            bfr[j] = *(const short8*)(Bp + (wc * 32 + j * 16 + r) * BK + q * 8);
#pragma unroll
        for (int i = 0; i < 4; ++i)
#pragma unroll
            for (int j = 0; j < 2; ++j)
                acc[i][j] = __builtin_amdgcn_mfma_f32_16x16x32_bf16(af[i], bfr[j], acc[i][j], 0, 0, 0);
    }

#pragma unroll
    for (int i = 0; i < 4; ++i) {
        int mrow = m0 + wr * 64 + i * 16 + q * 4;
#pragma unroll
        for (int j = 0; j < 2; ++j) {
            int ncol = n0 + wc * 32 + j * 16 + r;
            if (ncol < Nvalid) {
#pragma unroll
                for (int rr = 0; rr < 4; ++rr) {
                    float v = acc[i][j][rr];
                    int m = mrow + rr;
                    if (EPI == 1) {
                        v += bias[ncol];
                        v = v > 20.f ? v : log1pf(__expf(v));
                    }
                    if (EPI == 2) atomicAdd(&C[(long)m * ldc + ncol], v);
                    else C[(long)m * ldc + ncol] = v;
                }
            }
        }
    }
}

// ---------------- 128x128-tile GEMM, per-wave 64x64 ----------------
template <int ITERS>
__global__ __launch_bounds__(256, 1) void gemm128(
    const __hip_bfloat16* __restrict__ A, int lda,
    const float* __restrict__ Bw, int ldb, int Brows,
    float* __restrict__ C, int ldc, long zstride) {
    __shared__ __align__(16) __hip_bfloat16 As[2][128 * BK];
    __shared__ __align__(16) __hip_bfloat16 Bs[2][128 * BK];
    int tid = threadIdx.x;
    int wave = tid >> 6, lane = tid & 63;

    int gxy = gridDim.x * gridDim.y;
    int total = gxy * gridDim.z;
    int flat = (blockIdx.z * gridDim.y + blockIdx.y) * gridDim.x + blockIdx.x;
    int bm, bn, bz;
    if ((total & 7) == 0) {
        int lid = (flat & 7) * (total >> 3) + (flat >> 3);
        bz = lid / gxy;
        int rem = lid - bz * gxy;
        bn = rem / gridDim.y;
        bm = rem - bn * gridDim.y;
    } else {
        bm = blockIdx.y; bn = blockIdx.x; bz = blockIdx.z;
    }

    int m0 = bm * 128, n0 = bn * 128;
    int k_base = bz * (ITERS * BK);
    C += (long)bz * zstride;
    int wr = wave >> 1, wc = wave & 1;
    int srow = lane >> 2, scol = (lane & 3) * 8;
    int q = lane >> 4, r = lane & 15;

    floatx4 acc[4][4] = {};

    const __hip_bfloat16* gA0 = A + (long)(m0 + wave * 32 + srow) * lda + scol + k_base;
    const __hip_bfloat16* gA1 = gA0 + (long)16 * lda;
    int bn0 = n0 + wave * 32 + srow;
    const float* gB0 = Bw + (long)bn0 * ldb + scol + k_base;
    const float* gB1 = gB0 + (long)16 * ldb;
    bool bok0 = bn0 < Brows, bok1 = (bn0 + 16) < Brows;

    short8 qa0[DIST], qa1[DIST];
    floatx4 qb0[DIST] = {}, qb1[DIST] = {}, qb2[DIST] = {}, qb3[DIST] = {};

    auto ld = [&](int j) {
        int k0 = j * BK;
        int s = j & (DIST - 1);
        qa0[s] = *(const short8*)(gA0 + k0);
        qa1[s] = *(const short8*)(gA1 + k0);
        if (bok0) {
            qb0[s] = *(const floatx4*)(gB0 + k0);
            qb1[s] = *(const floatx4*)(gB0 + k0 + 4);
        }
        if (bok1) {
            qb2[s] = *(const floatx4*)(gB1 + k0);
            qb3[s] = *(const floatx4*)(gB1 + k0 + 4);
        }
    };
    auto wrstage = [&](int j) {
        int p = j & 1, s = j & (DIST - 1);
        *(short8*)(&As[p][(wave * 32 + srow) * BK + scol]) = qa0[s];
        *(short8*)(&As[p][(wave * 32 + 16 + srow) * BK + scol]) = qa1[s];
        *(short8*)(&Bs[p][(wave * 32 + srow) * BK + scol]) = pack8(qb0[s], qb1[s]);
        *(short8*)(&Bs[p][(wave * 32 + 16 + srow) * BK + scol]) = pack8(qb2[s], qb3[s]);
    };

#pragma unroll
    for (int j = 0; j < DIST; ++j)
        if (j < ITERS) ld(j);
    wrstage(0);

#pragma unroll
    for (int k = 0; k < ITERS; ++k) {
        BARRIER_NODRAIN();
        if (k + DIST < ITERS) ld(k + DIST);
        if (k + 1 < ITERS) wrstage(k + 1);
        const short* Ap = (const short*)As[k & 1];
        const short* Bp = (const short*)Bs[k & 1];
        short8 af[4], bfr[4];
#pragma unroll
        for (int i = 0; i < 4; ++i)
            af[i] = *(const short8*)(Ap + (wr * 64 + i * 16 + r) * BK + q * 8);
#pragma unroll
        for (int j = 0; j < 4; ++j)
            bfr[j] = *(const short8*)(Bp + (wc * 64 + j * 16 + r) * BK + q * 8);
#pragma unroll
        for (int i = 0; i < 4; ++i)
#pragma unroll
            for (int j = 0; j < 4; ++j)
                acc[i][j] = __builtin_amdgcn_mfma_f32_16x16x32_bf16(af[i], bfr[j], acc[i][j], 0, 0, 0);
    }

#pragma unroll
    for (int i = 0; i < 4; ++i) {
        int mrow = m0 + wr * 64 + i * 16 + q * 4;
#pragma unroll
        for (int j = 0; j < 4; ++j) {
            int ncol = n0 + wc * 64 + j * 16 + r;
#pragma unroll
            for (int rr = 0; rr < 4; ++rr)
                C[(long)(mrow + rr) * ldc + ncol] = acc[i][j][rr];
        }
    }
}

// ---------------- split-K reduce + residual (+fused RMSNorm for next layer) ----------------
template <int NPART, bool NORM>
__global__ __launch_bounds__(256) void reduce_kernel(const float* __restrict__ part2,
                                                     const float* __restrict__ xin,
                                                     const float* __restrict__ nw,
                                                     float* __restrict__ out,
                                                     __hip_bfloat16* __restrict__ xn) {
    int row = blockIdx.x;
    const float* xr = xin + (size_t)row * D;
    float v[4];
    float ss = 0.f;
#pragma unroll
    for (int i = 0; i < 4; ++i) {
        int c = threadIdx.x + i * 256;
        float s = xr[c];
#pragma unroll
        for (int p = 0; p < NPART; ++p)
            s += part2[(size_t)p * L * D + (size_t)row * D + c];
        v[i] = s;
        out[(size_t)row * D + c] = s;
        ss += s * s;
    }
    if (NORM) {
#pragma unroll
        for (int off = 32; off > 0; off >>= 1) ss += __shfl_xor(ss, off, 64);
        __shared__ float red[4];
        int wave = threadIdx.x >> 6;
        if ((threadIdx.x & 63) == 0) red[wave] = ss;
        __syncthreads();
        float inv = rsqrtf((red[0] + red[1] + red[2] + red[3]) * (1.f / D) + 1e-5f);
#pragma unroll
        for (int i = 0; i < 4; ++i) {
            int c = threadIdx.x + i * 256;
            xn[(size_t)row * D + c] = __float2bfloat16(v[i] * inv * nw[c]);
        }
    }
}

// ---------------- causal depthwise conv + bias + SiLU -> bf16; spare blocks zero xdbl96 ----------------
__global__ __launch_bounds__(256) void conv_silu_kernel(const float* __restrict__ xz,
                                                        const float* __restrict__ cw,
                                                        const float* __restrict__ cb,
                                                        __hip_bfloat16* __restrict__ u,
                                                        float* __restrict__ xdbl96) {
    int idx = blockIdx.x * 256 + threadIdx.x;  // t*DI + d
    if (blockIdx.x < (L * XD) / 256) xdbl96[idx] = 0.f;
    int d = idx & (DI - 1);
    int t = idx >> 11;
    float acc = cb[d];
#pragma unroll
    for (int k = 0; k < KCONV; ++k) {
        int tk = t - (KCONV - 1) + k;
        if (tk >= 0) acc += xz[(size_t)tk * (2 * DI) + d] * cw[d * KCONV + k];
    }
    u[idx] = __float2bfloat16(siluf(acc));
}

// ---------------- fused selective scan: A (local) -> flags -> B (combine) -> flags -> C (replay) ----
// Grid 512 = 8 dgroups x 64 chunks, all co-resident (launch_bounds(256,2), 2KB LDS).
// Cross-block data (Ach/Bch/Hinit) moves via sc1 (device-scope) accesses; flags are
// monotonic (value = layer+1) so they need zeroing only once per launch (rmsnorm0).
__global__ __launch_bounds__(256, 2) void scan_fused(
    const float* __restrict__ delta, const __hip_bfloat16* __restrict__ u,
    const float* __restrict__ xdbl96, const float* __restrict__ Alog,
    const float* __restrict__ xz, const float* __restrict__ Dskip,
    float* __restrict__ Ach, float* __restrict__ Bch,
    __hip_bfloat16* __restrict__ yg,
    uint32_t* __restrict__ flagsA, uint32_t* __restrict__ flagsB, int layer) {
    const int bid = blockIdx.x, tid = threadIdx.x;
    const int g = bid & 7, c = bid >> 3;
    const int d = g * 256 + tid;
    const uint32_t tgt = (uint32_t)(layer + 1);
    __shared__ __align__(16) float Bsh[CT * NSTATE];
    __shared__ __align__(16) float Csh[CT * NSTATE];

    float aval[NSTATE];
    {
        const floatx4* Al4 = (const floatx4*)(Alog + (size_t)d * NSTATE);
#pragma unroll
        for (int n4 = 0; n4 < 4; ++n4) {
            floatx4 t = Al4[n4];
            aval[n4 * 4 + 0] = -__expf(t[0]);
            aval[n4 * 4 + 1] = -__expf(t[1]);
            aval[n4 * 4 + 2] = -__expf(t[2]);
            aval[n4 * 4 + 3] = -__expf(t[3]);
        }
    }

    // ---- phase A: chunk-local scan, publish (a_prod, h_final) ----
    {
        Bsh[tid] = xdbl96[(size_t)(c * CT + (tid >> 4)) * XD + DTR + (tid & 15)];
        __syncthreads();
        float h[NSTATE], ap[NSTATE];
#pragma unroll
        for (int n = 0; n < NSTATE; ++n) { h[n] = 0.f; ap[n] = 1.f; }
        for (int tt = 0; tt < CT; ++tt) {
            int t = c * CT + tt;
            float dl = delta[(size_t)t * DI + d];
            float uu = __bfloat162float(u[(size_t)t * DI + d]);
            float du = dl * uu;
            const floatx4* Bv = (const floatx4*)(Bsh + tt * NSTATE);
#pragma unroll
            for (int n4 = 0; n4 < 4; ++n4) {
                floatx4 b = Bv[n4];
#pragma unroll
                for (int k = 0; k < 4; ++k) {
                    int n = n4 * 4 + k;
                    float a = __expf(dl * aval[n]);
                    h[n] = a * h[n] + du * b[k];
                    ap[n] *= a;
                }
            }
        }
        float* Ao = Ach + ((size_t)c * DI + d) * NSTATE;
        float* Bo = Bch + ((size_t)c * DI + d) * NSTATE;
#pragma unroll
        for (int n2 = 0; n2 < 8; ++n2) {
            union { float f[2]; uint64_t u; } ca, cb2;
            ca.f[0] = ap[n2 * 2]; ca.f[1] = ap[n2 * 2 + 1];
            cb2.f[0] = h[n2 * 2]; cb2.f[1] = h[n2 * 2 + 1];
            st_dev_u64(Ao + n2 * 2, ca.u);
            st_dev_u64(Bo + n2 * 2, cb2.u);
        }
        asm volatile("s_waitcnt vmcnt(0)" ::: "memory");
        __syncthreads();                       // all threads' publishes drained
        if (tid == 0) st_dev_u32(&flagsA[c * 8 + g], tgt);
    }

    // ---- phase B: 128 worker blocks combine chunks (i = d*16+n ranges) ----
    if (bid < 128) {
        int gb = bid >> 4;                     // dgroup whose aggregates we need
        if (tid < 64) {
            while (ld_dev_u32(&flagsA[tid * 8 + gb]) < tgt)
                __builtin_amdgcn_s_sleep(8);
        }
        __syncthreads();
        long i = (long)bid * 256 + tid;
        const long S = (long)DI * NSTATE;
        constexpr int P = 8;
        float ab[P], bb[P];
#pragma unroll
        for (int j = 0; j < P; ++j) {
            ab[j] = ld_dev_f(Ach + (long)j * S + i);
            bb[j] = ld_dev_f(Bch + (long)j * S + i);
        }
        float h = 0.f;
#pragma unroll
        for (int cc = 0; cc < NC; ++cc) {
            float a = ab[cc & (P - 1)];
            float b = bb[cc & (P - 1)];
            st_dev_f(Ach + (long)cc * S + i, h);   // becomes Hinit
            if (cc + P < NC) {
                ab[cc & (P - 1)] = ld_dev_f(Ach + (long)(cc + P) * S + i);
                bb[cc & (P - 1)] = ld_dev_f(Bch + (long)(cc + P) * S + i);
            }
            h = a * h + b;
        }
        asm volatile("s_waitcnt vmcnt(0)" ::: "memory");
        __syncthreads();
        if (tid == 0) st_dev_u32(&flagsB[bid], tgt);
    }

    // ---- phase C: wait for Hinit of our d-range, replay + gate -> yg ----
    {
        if (tid < 16) {
            while (ld_dev_u32(&flagsB[g * 16 + tid]) < tgt)
                __builtin_amdgcn_s_sleep(8);
        }
        __syncthreads();
        Bsh[tid] = xdbl96[(size_t)(c * CT + (tid >> 4)) * XD + DTR + (tid & 15)];
        Csh[tid] = xdbl96[(size_t)(c * CT + (tid >> 4)) * XD + DTR + 16 + (tid & 15)];
        __syncthreads();

        float h[NSTATE];
        {
            const float* Hi = Ach + ((size_t)c * DI + d) * NSTATE;
#pragma unroll
            for (int n2 = 0; n2 < 8; ++n2) {
                union { uint64_t u; float f[2]; } cv;
                cv.u = ld_dev_u64(Hi + n2 * 2);
                h[n2 * 2] = cv.f[0]; h[n2 * 2 + 1] = cv.f[1];
            }
        }
        float dsk = Dskip[d];
        for (int tt = 0; tt < CT; ++tt) {
            int t = c * CT + tt;
            float dl = delta[(size_t)t * DI + d];
            float uu = __bfloat162float(u[(size_t)t * DI + d]);
            float du = dl * uu;
            const floatx4* Bv = (const floatx4*)(Bsh + tt * NSTATE);
            const floatx4* Cv = (const floatx4*)(Csh + tt * NSTATE);
            float y = 0.f;
#pragma unroll
            for (int n4 = 0; n4 < 4; ++n4) {
                floatx4 b = Bv[n4];
                floatx4 cc = Cv[n4];
#pragma unroll
                for (int k = 0; k < 4; ++k) {
                    int n = n4 * 4 + k;
                    float a = __expf(dl * aval[n]);
                    h[n] = a * h[n] + du * b[k];
                    y += h[n] * cc[k];
                }
            }
            float z = xz[(size_t)t * (2 * DI) + DI + d];
            yg[(size_t)t * DI + d] = __float2bfloat16((y + uu * dsk) * siluf(z));
        }
    }
}

// ---------------- host orchestration ----------------
extern "C" void kernel_launch(void* const* d_in, const int* in_sizes, int n_in,
                              void* d_out, int out_size, void* d_ws, size_t ws_size,
                              hipStream_t stream) {
    const float* x      = (const float*)d_in[0];
    const float* norm_w = (const float*)d_in[1];
    const float* in_w   = (const float*)d_in[2];
    const float* conv_w = (const float*)d_in[3];
    const float* conv_b = (const float*)d_in[4];
    const float* xproj_w= (const float*)d_in[5];
    const float* dt_w   = (const float*)d_in[6];
    const float* dt_b   = (const float*)d_in[7];
    const float* A_log  = (const float*)d_in[8];
    const float* D_skip = (const float*)d_in[9];
    const float* out_w  = (const float*)d_in[10];
    float* out = (float*)d_out;

    uint8_t* wp = (uint8_t*)d_ws;
    auto alloc = [&](size_t bytes) {
        uint8_t* p = wp;
        wp += (bytes + 255) & ~(size_t)255;
        return p;
    };
    __hip_bfloat16* xn_bf   = (__hip_bfloat16*)alloc((size_t)L * D * 2);
    float*          xz      = (float*)alloc((size_t)L * 2 * DI * 4);
    __hip_bfloat16* u_bf    = (__hip_bfloat16*)alloc((size_t)L * DI * 2);
    float*          xdbl96  = (float*)alloc((size_t)L * XD * 4);
    float*          delta   = (float*)alloc((size_t)L * DI * 4);
    __hip_bfloat16* yg_bf   = (__hip_bfloat16*)alloc((size_t)L * DI * 2);
    float*          part2   = (float*)alloc((size_t)OSPLIT * L * D * 4);
    float*          Ach     = (float*)alloc((size_t)NC * DI * NSTATE * 4);  // Hinit aliases this
    float*          Bch     = (float*)alloc((size_t)NC * DI * NSTATE * 4);
    uint32_t*       flags   = (uint32_t*)alloc(768 * 4);   // flagsA[512] + flagsB[128] (+pad)

    // layer-0 RMSNorm; block 0 zeroes the scan flags (monotonic per layer afterwards)
    rmsnorm_kernel<<<L, 256, 0, stream>>>(x, norm_w, xn_bf, flags);

    for (int l = 0; l < NLAYER; ++l) {
        const float* xin = (l == 0) ? x : out;

        // in_proj: [1024,1024] x [4096,1024]^T -> xz  (128x128 tiles, 256 blocks, 32 iters)
        gemm128<32><<<dim3(4096 / 128, L / 128, 1), 256, 0, stream>>>(
            xn_bf, D, in_w + (size_t)l * 4096 * 1024, D, 4096, xz, 4096, 0);

        // conv+SiLU -> u; spare blocks zero xdbl96 for the atomic split-K below
        conv_silu_kernel<<<L * DI / 256, 256, 0, stream>>>(
            xz, conv_w + (size_t)l * DI * KCONV, conv_b + (size_t)l * DI, u_bf, xdbl96);

        // x_proj split-K=16, atomicAdd epilogue -> xdbl96[L][96]  (256 blocks, 4 iters)
        gemm_pipe<2, 2048 / (KSPLIT * BK), false, 4><<<dim3(2, L / 128, KSPLIT), 256, 0, stream>>>(
            u_bf, DI, xproj_w + (size_t)l * 96 * 2048, DI, 96,
            xdbl96, XD, XD, nullptr);

        // dt_proj: A = xdbl96 f32 (converted in staging), softplus(+bias) -> delta  (2 iters)
        gemm_pipe<1, 2, true, 2><<<dim3(2048 / 64, L / 128, 1), 256, 0, stream>>>(
            xdbl96, XD, dt_w + (size_t)l * 2048 * 64, DTR, 2048,
            delta, DI, DI, dt_b + (size_t)l * DI);

        // fused scan (A + B + C with in-kernel flag sync)
        scan_fused<<<512, 256, 0, stream>>>(
            delta, u_bf, xdbl96, A_log + (size_t)l * DI * NSTATE, xz,
            D_skip + (size_t)l * DI, Ach, Bch, yg_bf, flags, flags + 512, l);

        // out_proj split-K=4 -> part2 (plain stores; 256 blocks, 16 iters)
        gemm128<2048 / (OSPLIT * BK)><<<dim3(1024 / 128, L / 128, OSPLIT), 256, 0, stream>>>(
            yg_bf, DI, out_w + (size_t)l * 1024 * 2048, DI, 1024,
            part2, D, (long)L * D);

        // reduce + residual (+RMSNorm input for next layer)
        if (l < NLAYER - 1)
            reduce_kernel<OSPLIT, true><<<L, 256, 0, stream>>>(
                part2, xin, norm_w + (size_t)(l + 1) * D, out, xn_bf);
        else
            reduce_kernel<OSPLIT, false><<<L, 256, 0, stream>>>(
                part2, xin, nullptr, out, nullptr);
    }
}

// Round 7
// 675.730 us; speedup vs baseline: 1.0985x; 1.0985x over previous
//
#include <hip/hip_runtime.h>
#include <hip/hip_bf16.h>
#include <stdint.h>

#define L 1024
#define D 1024
#define NLAYER 4
#define NSTATE 16
#define DI 2048
#define DTR 64
#define KCONV 4
#define XD 96      // DTR + 2*NSTATE
#define NC 64      // scan chunks
#define CT 16      // timesteps per chunk (L/NC)
#define KSPLIT 8   // x_proj split-K (plain stores -> part)
#define OSPLIT 4   // out_proj split-K (part2 + reduce)
#define BK 32
#define DIST 4     // GEMM prefetch depth (iterations)

typedef __attribute__((ext_vector_type(8))) short short8;
typedef __attribute__((ext_vector_type(4))) float floatx4;

__device__ __forceinline__ float siluf(float x) { return x / (1.f + __expf(-x)); }

__device__ __forceinline__ unsigned short f2bf(float x) {
    __hip_bfloat16 b = __float2bfloat16(x);
    return *reinterpret_cast<unsigned short*>(&b);
}

__device__ __forceinline__ short8 pack8(floatx4 a, floatx4 b) {
    short8 o;
    o[0] = (short)f2bf(a.x); o[1] = (short)f2bf(a.y);
    o[2] = (short)f2bf(a.z); o[3] = (short)f2bf(a.w);
    o[4] = (short)f2bf(b.x); o[5] = (short)f2bf(b.y);
    o[6] = (short)f2bf(b.z); o[7] = (short)f2bf(b.w);
    return o;
}

// ---------- device-scope (sc1) accessors for cross-block traffic within one dispatch ----------
__device__ __forceinline__ void st_dev_u32(uint32_t* p, uint32_t v) {
    __hip_atomic_store(p, v, __ATOMIC_RELAXED, __HIP_MEMORY_SCOPE_AGENT);
}
__device__ __forceinline__ uint32_t ld_dev_u32(const uint32_t* p) {
    return __hip_atomic_load(p, __ATOMIC_RELAXED, __HIP_MEMORY_SCOPE_AGENT);
}
__device__ __forceinline__ void st_dev_u64(void* p, uint64_t v) {
    __hip_atomic_store((unsigned long long*)p, (unsigned long long)v, __ATOMIC_RELAXED, __HIP_MEMORY_SCOPE_AGENT);
}
__device__ __forceinline__ uint64_t ld_dev_u64(const void* p) {
    return (uint64_t)__hip_atomic_load((const unsigned long long*)p, __ATOMIC_RELAXED, __HIP_MEMORY_SCOPE_AGENT);
}
__device__ __forceinline__ float ld_dev_f(const float* p) {
    uint32_t u = ld_dev_u32((const uint32_t*)p);
    union { uint32_t u; float f; } c; c.u = u;
    return c.f;
}
__device__ __forceinline__ void st_dev_f(float* p, float v) {
    union { float f; uint32_t u; } c; c.f = v;
    st_dev_u32((uint32_t*)p, c.u);
}

// Barrier that does NOT drain vmcnt: deep global-load prefetches stay in flight.
#define BARRIER_NODRAIN() asm volatile("s_waitcnt lgkmcnt(0)\n\ts_barrier" ::: "memory")

// ---------------- RMSNorm (layer 0) -> bf16; block 0 also zeroes the scan flags ----------------
__global__ __launch_bounds__(256) void rmsnorm_kernel(const float* __restrict__ x,
                                                      const float* __restrict__ w,
                                                      __hip_bfloat16* __restrict__ xn,
                                                      uint32_t* __restrict__ flags) {
    if (blockIdx.x == 0) {
#pragma unroll
        for (int i = 0; i < 3; ++i) st_dev_u32(&flags[threadIdx.x + i * 256], 0u);
    }
    int row = blockIdx.x;
    const float* xr = x + (size_t)row * D;
    float v[4];
    float s = 0.f;
#pragma unroll
    for (int i = 0; i < 4; ++i) {
        v[i] = xr[threadIdx.x + i * 256];
        s += v[i] * v[i];
    }
#pragma unroll
    for (int off = 32; off > 0; off >>= 1) s += __shfl_xor(s, off, 64);
    __shared__ float red[4];
    int wave = threadIdx.x >> 6;
    if ((threadIdx.x & 63) == 0) red[wave] = s;
    __syncthreads();
    float inv = rsqrtf((red[0] + red[1] + red[2] + red[3]) * (1.f / D) + 1e-5f);
#pragma unroll
    for (int i = 0; i < 4; ++i) {
        int c = threadIdx.x + i * 256;
        xn[(size_t)row * D + c] = __float2bfloat16(v[i] * inv * w[c]);
    }
}

// ---------------- pipelined GEMM (128x64 tile): C[M,N] = A[M,K] * B[N,K]^T ----------------
// ASUM=false: A bf16. ASUM=true: A = f32 sum of KSPLIT partial buffers (stride astride),
// converted to bf16 during staging. EPI: 0 plain store; 1 softplus(c + bias[n]).
template <int EPI, bool ASUM, int ITERS, int QD>
__global__ __launch_bounds__(256, 2) void gemm_pipe(
    const void* __restrict__ Aptr, int lda, long astride,
    const float* __restrict__ Bw, int ldb, int Brows,
    float* __restrict__ C, int ldc, int Nvalid, long zstride,
    const float* __restrict__ bias) {
    __shared__ __align__(16) __hip_bfloat16 As[2][128 * BK];
    __shared__ __align__(16) __hip_bfloat16 Bs[2][64 * BK];
    int tid = threadIdx.x;
    int wave = tid >> 6, lane = tid & 63;

    int gxy = gridDim.x * gridDim.y;
    int total = gxy * gridDim.z;
    int flat = (blockIdx.z * gridDim.y + blockIdx.y) * gridDim.x + blockIdx.x;
    int bm, bn, bz;
    if ((total & 7) == 0) {
        int lid = (flat & 7) * (total >> 3) + (flat >> 3);
        bz = lid / gxy;
        int rem = lid - bz * gxy;
        bn = rem / gridDim.y;
        bm = rem - bn * gridDim.y;
    } else {
        bm = blockIdx.y; bn = blockIdx.x; bz = blockIdx.z;
    }

    int m0 = bm * 128, n0 = bn * 64;
    int k_base = bz * (ITERS * BK);
    C += (long)bz * zstride;
    int wr = wave >> 1, wc = wave & 1;
    int srow = lane >> 2, scol = (lane & 3) * 8;
    int q = lane >> 4, r = lane & 15;

    floatx4 acc[4][2] = {};

    int arow0 = m0 + wave * 32 + srow;
    const __hip_bfloat16* gA0 = nullptr; const __hip_bfloat16* gA1 = nullptr;
    const float* gAf0 = nullptr; const float* gAf1 = nullptr;
    if (ASUM) {
        gAf0 = (const float*)Aptr + (long)arow0 * lda + scol + k_base;
        gAf1 = gAf0 + (long)16 * lda;
    } else {
        gA0 = (const __hip_bfloat16*)Aptr + (long)arow0 * lda + scol + k_base;
        gA1 = gA0 + (long)16 * lda;
    }
    int bnrow = n0 + wave * 16 + srow;
    const float* gB = Bw + (long)bnrow * ldb + scol + k_base;
    bool bok = bnrow < Brows;

    short8 qa0[QD], qa1[QD];
    floatx4 qaf[ASUM ? QD : 1][4];
    floatx4 qb0[QD] = {}, qb1[QD] = {};

    auto ld = [&](int j) {
        int k0 = j * BK;
        int s = j & (QD - 1);
        if (ASUM) {
            floatx4 t0 = *(const floatx4*)(gAf0 + k0);
            floatx4 t1 = *(const floatx4*)(gAf0 + k0 + 4);
            floatx4 t2 = *(const floatx4*)(gAf1 + k0);
            floatx4 t3 = *(const floatx4*)(gAf1 + k0 + 4);
#pragma unroll
            for (int sp = 1; sp < KSPLIT; ++sp) {
                t0 += *(const floatx4*)(gAf0 + sp * astride + k0);
                t1 += *(const floatx4*)(gAf0 + sp * astride + k0 + 4);
                t2 += *(const floatx4*)(gAf1 + sp * astride + k0);
                t3 += *(const floatx4*)(gAf1 + sp * astride + k0 + 4);
            }
            qaf[s][0] = t0; qaf[s][1] = t1; qaf[s][2] = t2; qaf[s][3] = t3;
        } else {
            qa0[s] = *(const short8*)(gA0 + k0);
            qa1[s] = *(const short8*)(gA1 + k0);
        }
        if (bok) {
            qb0[s] = *(const floatx4*)(gB + k0);
            qb1[s] = *(const floatx4*)(gB + k0 + 4);
        }
    };
    auto wrstage = [&](int j) {
        int p = j & 1, s = j & (QD - 1);
        if (ASUM) {
            *(short8*)(&As[p][(wave * 32 + srow) * BK + scol]) = pack8(qaf[s][0], qaf[s][1]);
            *(short8*)(&As[p][(wave * 32 + 16 + srow) * BK + scol]) = pack8(qaf[s][2], qaf[s][3]);
        } else {
            *(short8*)(&As[p][(wave * 32 + srow) * BK + scol]) = qa0[s];
            *(short8*)(&As[p][(wave * 32 + 16 + srow) * BK + scol]) = qa1[s];
        }
        *(short8*)(&Bs[p][(wave * 16 + srow) * BK + scol]) = pack8(qb0[s], qb1[s]);
    };

#pragma unroll
    for (int j = 0; j < QD; ++j)
        if (j < ITERS) ld(j);
    wrstage(0);

#pragma unroll
    for (int k = 0; k < ITERS; ++k) {
        BARRIER_NODRAIN();
        if (k + QD < ITERS) ld(k + QD);
        if (k + 1 < ITERS) wrstage(k + 1);
        const short* Ap = (const short*)As[k & 1];
        const short* Bp = (const short*)Bs[k & 1];
        short8 af[4], bfr[2];
#pragma unroll
        for (int i = 0; i < 4; ++i)
            af[i] = *(const short8*)(Ap + (wr * 64 + i * 16 + r) * BK + q * 8);
#pragma unroll
        for (int j = 0; j < 2; ++j)
            bfr[j] = *(const short8*)(Bp + (wc * 32 + j * 16 + r) * BK + q * 8);
#pragma unroll
        for (int i = 0; i < 4; ++i)
#pragma unroll
            for (int j = 0; j < 2; ++j)
                acc[i][j] = __builtin_amdgcn_mfma_f32_16x16x32_bf16(af[i], bfr[j], acc[i][j], 0, 0, 0);
    }

#pragma unroll
    for (int i = 0; i < 4; ++i) {
        int mrow = m0 + wr * 64 + i * 16 + q * 4;
#pragma unroll
        for (int j = 0; j < 2; ++j) {
            int ncol = n0 + wc * 32 + j * 16 + r;
            if (ncol < Nvalid) {
#pragma unroll
                for (int rr = 0; rr < 4; ++rr) {
                    float v = acc[i][j][rr];
                    int m = mrow + rr;
                    if (EPI == 1) {
                        v += bias[ncol];
                        v = v > 20.f ? v : log1pf(__expf(v));
                    }
                    C[(long)m * ldc + ncol] = v;
                }
            }
        }
    }
}

// ---------------- 128x128-tile GEMM, per-wave 64x64 ----------------
template <int ITERS>
__global__ __launch_bounds__(256, 1) void gemm128(
    const __hip_bfloat16* __restrict__ A, int lda,
    const float* __restrict__ Bw, int ldb, int Brows,
    float* __restrict__ C, int ldc, long zstride) {
    __shared__ __align__(16) __hip_bfloat16 As[2][128 * BK];
    __shared__ __align__(16) __hip_bfloat16 Bs[2][128 * BK];
    int tid = threadIdx.x;
    int wave = tid >> 6, lane = tid & 63;

    int gxy = gridDim.x * gridDim.y;
    int total = gxy * gridDim.z;
    int flat = (blockIdx.z * gridDim.y + blockIdx.y) * gridDim.x + blockIdx.x;
    int bm, bn, bz;
    if ((total & 7) == 0) {
        int lid = (flat & 7) * (total >> 3) + (flat >> 3);
        bz = lid / gxy;
        int rem = lid - bz * gxy;
        bn = rem / gridDim.y;
        bm = rem - bn * gridDim.y;
    } else {
        bm = blockIdx.y; bn = blockIdx.x; bz = blockIdx.z;
    }

    int m0 = bm * 128, n0 = bn * 128;
    int k_base = bz * (ITERS * BK);
    C += (long)bz * zstride;
    int wr = wave >> 1, wc = wave & 1;
    int srow = lane >> 2, scol = (lane & 3) * 8;
    int q = lane >> 4, r = lane & 15;

    floatx4 acc[4][4] = {};

    const __hip_bfloat16* gA0 = A + (long)(m0 + wave * 32 + srow) * lda + scol + k_base;
    const __hip_bfloat16* gA1 = gA0 + (long)16 * lda;
    int bn0 = n0 + wave * 32 + srow;
    const float* gB0 = Bw + (long)bn0 * ldb + scol + k_base;
    const float* gB1 = gB0 + (long)16 * ldb;
    bool bok0 = bn0 < Brows, bok1 = (bn0 + 16) < Brows;

    short8 qa0[DIST], qa1[DIST];
    floatx4 qb0[DIST] = {}, qb1[DIST] = {}, qb2[DIST] = {}, qb3[DIST] = {};

    auto ld = [&](int j) {
        int k0 = j * BK;
        int s = j & (DIST - 1);
        qa0[s] = *(const short8*)(gA0 + k0);
        qa1[s] = *(const short8*)(gA1 + k0);
        if (bok0) {
            qb0[s] = *(const floatx4*)(gB0 + k0);
            qb1[s] = *(const floatx4*)(gB0 + k0 + 4);
        }
        if (bok1) {
            qb2[s] = *(const floatx4*)(gB1 + k0);
            qb3[s] = *(const floatx4*)(gB1 + k0 + 4);
        }
    };
    auto wrstage = [&](int j) {
        int p = j & 1, s = j & (DIST - 1);
        *(short8*)(&As[p][(wave * 32 + srow) * BK + scol]) = qa0[s];
        *(short8*)(&As[p][(wave * 32 + 16 + srow) * BK + scol]) = qa1[s];
        *(short8*)(&Bs[p][(wave * 32 + srow) * BK + scol]) = pack8(qb0[s], qb1[s]);
        *(short8*)(&Bs[p][(wave * 32 + 16 + srow) * BK + scol]) = pack8(qb2[s], qb3[s]);
    };

#pragma unroll
    for (int j = 0; j < DIST; ++j)
        if (j < ITERS) ld(j);
    wrstage(0);

#pragma unroll
    for (int k = 0; k < ITERS; ++k) {
        BARRIER_NODRAIN();
        if (k + DIST < ITERS) ld(k + DIST);
        if (k + 1 < ITERS) wrstage(k + 1);
        const short* Ap = (const short*)As[k & 1];
        const short* Bp = (const short*)Bs[k & 1];
        short8 af[4], bfr[4];
#pragma unroll
        for (int i = 0; i < 4; ++i)
            af[i] = *(const short8*)(Ap + (wr * 64 + i * 16 + r) * BK + q * 8);
#pragma unroll
        for (int j = 0; j < 4; ++j)
            bfr[j] = *(const short8*)(Bp + (wc * 64 + j * 16 + r) * BK + q * 8);
#pragma unroll
        for (int i = 0; i < 4; ++i)
#pragma unroll
            for (int j = 0; j < 4; ++j)
                acc[i][j] = __builtin_amdgcn_mfma_f32_16x16x32_bf16(af[i], bfr[j], acc[i][j], 0, 0, 0);
    }

#pragma unroll
    for (int i = 0; i < 4; ++i) {
        int mrow = m0 + wr * 64 + i * 16 + q * 4;
#pragma unroll
        for (int j = 0; j < 4; ++j) {
            int ncol = n0 + wc * 64 + j * 16 + r;
#pragma unroll
            for (int rr = 0; rr < 4; ++rr)
                C[(long)(mrow + rr) * ldc + ncol] = acc[i][j][rr];
        }
    }
}

// ---------------- split-K reduce + residual (+fused RMSNorm for next layer) ----------------
template <int NPART, bool NORM>
__global__ __launch_bounds__(256) void reduce_kernel(const float* __restrict__ part2,
                                                     const float* __restrict__ xin,
                                                     const float* __restrict__ nw,
                                                     float* __restrict__ out,
                                                     __hip_bfloat16* __restrict__ xn) {
    int row = blockIdx.x;
    const float* xr = xin + (size_t)row * D;
    float v[4];
    float ss = 0.f;
#pragma unroll
    for (int i = 0; i < 4; ++i) {
        int c = threadIdx.x + i * 256;
        float s = xr[c];
#pragma unroll
        for (int p = 0; p < NPART; ++p)
            s += part2[(size_t)p * L * D + (size_t)row * D + c];
        v[i] = s;
        out[(size_t)row * D + c] = s;
        ss += s * s;
    }
    if (NORM) {
#pragma unroll
        for (int off = 32; off > 0; off >>= 1) ss += __shfl_xor(ss, off, 64);
        __shared__ float red[4];
        int wave = threadIdx.x >> 6;
        if ((threadIdx.x & 63) == 0) red[wave] = ss;
        __syncthreads();
        float inv = rsqrtf((red[0] + red[1] + red[2] + red[3]) * (1.f / D) + 1e-5f);
#pragma unroll
        for (int i = 0; i < 4; ++i) {
            int c = threadIdx.x + i * 256;
            xn[(size_t)row * D + c] = __float2bfloat16(v[i] * inv * nw[c]);
        }
    }
}

// ---------------- causal depthwise conv + bias + SiLU -> bf16 ----------------
__global__ __launch_bounds__(256) void conv_silu_kernel(const float* __restrict__ xz,
                                                        const float* __restrict__ cw,
                                                        const float* __restrict__ cb,
                                                        __hip_bfloat16* __restrict__ u) {
    int idx = blockIdx.x * 256 + threadIdx.x;  // t*DI + d
    int d = idx & (DI - 1);
    int t = idx >> 11;
    float acc = cb[d];
#pragma unroll
    for (int k = 0; k < KCONV; ++k) {
        int tk = t - (KCONV - 1) + k;
        if (tk >= 0) acc += xz[(size_t)tk * (2 * DI) + d] * cw[d * KCONV + k];
    }
    u[idx] = __float2bfloat16(siluf(acc));
}

// ---------------- fused selective scan v2: coalesced sc1 via LDS bounce ----------------
// Grid 512 = 8 dgroups x 64 chunks, all co-resident (launch_bounds(256,2), ~18KB LDS).
// Cross-block data (Ach/Bch/Hinit) moves via COALESCED sc1 accesses (lane stride 8B);
// per-thread scatter/gather goes through an LDS bounce buffer. Flags are monotonic
// (value = layer+1), zeroed once per launch by rmsnorm. B/C columns of x_proj are
// summed from the 8 split-K partials in-block (replaces the xred kernel).
__global__ __launch_bounds__(256, 2) void scan_fused(
    const float* __restrict__ delta, const __hip_bfloat16* __restrict__ u,
    const float* __restrict__ part,   // [KSPLIT][L][XD]
    const float* __restrict__ Alog, const float* __restrict__ xz,
    const float* __restrict__ Dskip,
    float* __restrict__ Ach, float* __restrict__ Bch,
    __hip_bfloat16* __restrict__ yg,
    uint32_t* __restrict__ flagsA, uint32_t* __restrict__ flagsB, int layer) {
    const int bid = blockIdx.x, tid = threadIdx.x;
    const int g = bid & 7, c = bid >> 3;
    const int d = g * 256 + tid;
    const uint32_t tgt = (uint32_t)(layer + 1);
    __shared__ __align__(16) float Bsh[CT * NSTATE];
    __shared__ __align__(16) float Csh[CT * NSTATE];
    __shared__ __align__(16) float bounce[4096];   // 16KB

    // ---- B/C column sums for this chunk (replaces xred's BC half) ----
    for (int s2 = tid; s2 < CT * 32; s2 += 256) {
        int tt = s2 >> 5, col = s2 & 31;
        float sum = 0.f;
#pragma unroll
        for (int sp = 0; sp < KSPLIT; ++sp)
            sum += part[(size_t)sp * L * XD + (size_t)(c * CT + tt) * XD + DTR + col];
        if (col < 16) Bsh[tt * NSTATE + col] = sum;
        else          Csh[tt * NSTATE + (col - 16)] = sum;
    }
    __syncthreads();

    float aval[NSTATE];
    {
        const floatx4* Al4 = (const floatx4*)(Alog + (size_t)d * NSTATE);
#pragma unroll
        for (int n4 = 0; n4 < 4; ++n4) {
            floatx4 t = Al4[n4];
            aval[n4 * 4 + 0] = -__expf(t[0]);
            aval[n4 * 4 + 1] = -__expf(t[1]);
            aval[n4 * 4 + 2] = -__expf(t[2]);
            aval[n4 * 4 + 3] = -__expf(t[3]);
        }
    }

    // ---- phase A: chunk-local scan; publish (a_prod, h_final) coalesced ----
    {
        float h[NSTATE], ap[NSTATE];
#pragma unroll
        for (int n = 0; n < NSTATE; ++n) { h[n] = 0.f; ap[n] = 1.f; }
        for (int tt = 0; tt < CT; ++tt) {
            int t = c * CT + tt;
            float dl = delta[(size_t)t * DI + d];
            float uu = __bfloat162float(u[(size_t)t * DI + d]);
            float du = dl * uu;
            const floatx4* Bv = (const floatx4*)(Bsh + tt * NSTATE);
#pragma unroll
            for (int n4 = 0; n4 < 4; ++n4) {
                floatx4 b = Bv[n4];
#pragma unroll
                for (int k = 0; k < 4; ++k) {
                    int n = n4 * 4 + k;
                    float a = __expf(dl * aval[n]);
                    h[n] = a * h[n] + du * b[k];
                    ap[n] *= a;
                }
            }
        }
        // bounce ap -> coalesced sc1 store (block slab = 4096 floats, contiguous)
        uint64_t* gA = (uint64_t*)(Ach + ((size_t)c * DI + g * 256) * NSTATE);
        uint64_t* gB = (uint64_t*)(Bch + ((size_t)c * DI + g * 256) * NSTATE);
        {
            floatx4* bl = (floatx4*)(bounce + tid * NSTATE);
#pragma unroll
            for (int n4 = 0; n4 < 4; ++n4)
                bl[n4] = floatx4{ap[n4 * 4], ap[n4 * 4 + 1], ap[n4 * 4 + 2], ap[n4 * 4 + 3]};
        }
        __syncthreads();
        {
            const uint64_t* bb = (const uint64_t*)bounce;
#pragma unroll
            for (int w = 0; w < 8; ++w)
                st_dev_u64(gA + w * 256 + tid, bb[w * 256 + tid]);
        }
        __syncthreads();
        {
            floatx4* bl = (floatx4*)(bounce + tid * NSTATE);
#pragma unroll
            for (int n4 = 0; n4 < 4; ++n4)
                bl[n4] = floatx4{h[n4 * 4], h[n4 * 4 + 1], h[n4 * 4 + 2], h[n4 * 4 + 3]};
        }
        __syncthreads();
        {
            const uint64_t* bb = (const uint64_t*)bounce;
#pragma unroll
            for (int w = 0; w < 8; ++w)
                st_dev_u64(gB + w * 256 + tid, bb[w * 256 + tid]);
        }
        asm volatile("s_waitcnt vmcnt(0)" ::: "memory");
        __syncthreads();
        if (tid == 0) st_dev_u32(&flagsA[c * 8 + g], tgt);
    }

    // ---- phase B: 128 worker blocks combine chunks (coalesced 4B/lane) ----
    if (bid < 128) {
        int gb = bid >> 4;
        if (tid < 64) {
            while (ld_dev_u32(&flagsA[tid * 8 + gb]) < tgt)
                __builtin_amdgcn_s_sleep(8);
        }
        __syncthreads();
        long i = (long)bid * 256 + tid;
        const long S = (long)DI * NSTATE;
        constexpr int P = 8;
        float ab[P], bb[P];
#pragma unroll
        for (int j = 0; j < P; ++j) {
            ab[j] = ld_dev_f(Ach + (long)j * S + i);
            bb[j] = ld_dev_f(Bch + (long)j * S + i);
        }
        float h = 0.f;
#pragma unroll
        for (int cc = 0; cc < NC; ++cc) {
            float a = ab[cc & (P - 1)];
            float b = bb[cc & (P - 1)];
            st_dev_f(Ach + (long)cc * S + i, h);   // becomes Hinit
            if (cc + P < NC) {
                ab[cc & (P - 1)] = ld_dev_f(Ach + (long)(cc + P) * S + i);
                bb[cc & (P - 1)] = ld_dev_f(Bch + (long)(cc + P) * S + i);
            }
            h = a * h + b;
        }
        asm volatile("s_waitcnt vmcnt(0)" ::: "memory");
        __syncthreads();
        if (tid == 0) st_dev_u32(&flagsB[bid], tgt);
    }

    // ---- phase C: wait for Hinit, load coalesced via bounce, replay + gate -> yg ----
    {
        if (tid < 16) {
            while (ld_dev_u32(&flagsB[g * 16 + tid]) < tgt)
                __builtin_amdgcn_s_sleep(8);
        }
        __syncthreads();
        {
            const uint64_t* gH = (const uint64_t*)(Ach + ((size_t)c * DI + g * 256) * NSTATE);
            uint64_t hb[8];
#pragma unroll
            for (int w = 0; w < 8; ++w) hb[w] = ld_dev_u64(gH + w * 256 + tid);
            uint64_t* bb = (uint64_t*)bounce;
#pragma unroll
            for (int w = 0; w < 8; ++w) bb[w * 256 + tid] = hb[w];
        }
        __syncthreads();
        float h[NSTATE];
        {
            const float* bl = bounce + tid * NSTATE;
#pragma unroll
            for (int n = 0; n < NSTATE; ++n) h[n] = bl[n];
        }
        float dsk = Dskip[d];
        for (int tt = 0; tt < CT; ++tt) {
            int t = c * CT + tt;
            float dl = delta[(size_t)t * DI + d];
            float uu = __bfloat162float(u[(size_t)t * DI + d]);
            float du = dl * uu;
            const floatx4* Bv = (const floatx4*)(Bsh + tt * NSTATE);
            const floatx4* Cv = (const floatx4*)(Csh + tt * NSTATE);
            float y = 0.f;
#pragma unroll
            for (int n4 = 0; n4 < 4; ++n4) {
                floatx4 b = Bv[n4];
                floatx4 cc = Cv[n4];
#pragma unroll
                for (int k = 0; k < 4; ++k) {
                    int n = n4 * 4 + k;
                    float a = __expf(dl * aval[n]);
                    h[n] = a * h[n] + du * b[k];
                    y += h[n] * cc[k];
                }
            }
            float z = xz[(size_t)t * (2 * DI) + DI + d];
            yg[(size_t)t * DI + d] = __float2bfloat16((y + uu * dsk) * siluf(z));
        }
    }
}

// ---------------- host orchestration ----------------
extern "C" void kernel_launch(void* const* d_in, const int* in_sizes, int n_in,
                              void* d_out, int out_size, void* d_ws, size_t ws_size,
                              hipStream_t stream) {
    const float* x      = (const float*)d_in[0];
    const float* norm_w = (const float*)d_in[1];
    const float* in_w   = (const float*)d_in[2];
    const float* conv_w = (const float*)d_in[3];
    const float* conv_b = (const float*)d_in[4];
    const float* xproj_w= (const float*)d_in[5];
    const float* dt_w   = (const float*)d_in[6];
    const float* dt_b   = (const float*)d_in[7];
    const float* A_log  = (const float*)d_in[8];
    const float* D_skip = (const float*)d_in[9];
    const float* out_w  = (const float*)d_in[10];
    float* out = (float*)d_out;

    uint8_t* wp = (uint8_t*)d_ws;
    auto alloc = [&](size_t bytes) {
        uint8_t* p = wp;
        wp += (bytes + 255) & ~(size_t)255;
        return p;
    };
    __hip_bfloat16* xn_bf   = (__hip_bfloat16*)alloc((size_t)L * D * 2);
    float*          xz      = (float*)alloc((size_t)L * 2 * DI * 4);
    __hip_bfloat16* u_bf    = (__hip_bfloat16*)alloc((size_t)L * DI * 2);
    float*          part    = (float*)alloc((size_t)KSPLIT * L * XD * 4);
    float*          delta   = (float*)alloc((size_t)L * DI * 4);
    __hip_bfloat16* yg_bf   = (__hip_bfloat16*)alloc((size_t)L * DI * 2);
    float*          part2   = (float*)alloc((size_t)OSPLIT * L * D * 4);
    float*          Ach     = (float*)alloc((size_t)NC * DI * NSTATE * 4);  // Hinit aliases this
    float*          Bch     = (float*)alloc((size_t)NC * DI * NSTATE * 4);
    uint32_t*       flags   = (uint32_t*)alloc(768 * 4);   // flagsA[512] + flagsB[128] (+pad)

    // layer-0 RMSNorm; block 0 zeroes scan flags (monotonic across layers afterwards)
    rmsnorm_kernel<<<L, 256, 0, stream>>>(x, norm_w, xn_bf, flags);

    for (int l = 0; l < NLAYER; ++l) {
        const float* xin = (l == 0) ? x : out;

        // in_proj: [1024,1024] x [4096,1024]^T -> xz  (128x128 tiles, 256 blocks, 32 iters)
        gemm128<32><<<dim3(4096 / 128, L / 128, 1), 256, 0, stream>>>(
            xn_bf, D, in_w + (size_t)l * 4096 * 1024, D, 4096, xz, 4096, 0);

        conv_silu_kernel<<<L * DI / 256, 256, 0, stream>>>(
            xz, conv_w + (size_t)l * DI * KCONV, conv_b + (size_t)l * DI, u_bf);

        // x_proj split-K=8 -> part[s][1024][96]  (128 blocks, 8 iters each)
        gemm_pipe<0, false, 8, 4><<<dim3(2, L / 128, KSPLIT), 256, 0, stream>>>(
            u_bf, DI, 0, xproj_w + (size_t)l * 96 * 2048, DI, 96,
            part, XD, XD, (long)L * XD, nullptr);

        // dt_proj: A = sum of 8 part slabs (f32, packed to bf16 in staging), softplus(+bias)
        gemm_pipe<1, true, 2, 2><<<dim3(2048 / 64, L / 128, 1), 256, 0, stream>>>(
            part, XD, (long)L * XD, dt_w + (size_t)l * 2048 * 64, DTR, 2048,
            delta, DI, DI, 0, dt_b + (size_t)l * DI);

        // fused scan (A + B + C with flag sync; sums B/C columns from part in-block)
        scan_fused<<<512, 256, 0, stream>>>(
            delta, u_bf, part, A_log + (size_t)l * DI * NSTATE, xz,
            D_skip + (size_t)l * DI, Ach, Bch, yg_bf, flags, flags + 512, l);

        // out_proj split-K=4 -> part2  (128x128 tiles, 256 blocks, 16 iters)
        gemm128<2048 / (OSPLIT * BK)><<<dim3(1024 / 128, L / 128, OSPLIT), 256, 0, stream>>>(
            yg_bf, DI, out_w + (size_t)l * 1024 * 2048, DI, 1024,
            part2, D, (long)L * D);

        // reduce + residual (+RMSNorm input for next layer)
        if (l < NLAYER - 1)
            reduce_kernel<OSPLIT, true><<<L, 256, 0, stream>>>(
                part2, xin, norm_w + (size_t)(l + 1) * D, out, xn_bf);
        else
            reduce_kernel<OSPLIT, false><<<L, 256, 0, stream>>>(
                part2, xin, nullptr, out, nullptr);
    }
}